// Round 1
// baseline (1440.597 us; speedup 1.0000x reference)
//
#include <hip/hip_runtime.h>
#include <math.h>

#define BB 4
#define CC 64
#define TT 128
#define QQ 128
#define KK 8
#define HH 128
#define DIN 512
#define LL 121
#define NN 512
#define FOURH 512
#define TWOH 256
#define LPAD 135   // Q + K - 1 rows (7 zero pad + 121 + 7 zero pad)

// ---------------- LayerNorm over channel dim ----------------
__global__ __launch_bounds__(256)
void ln_kernel(const float* __restrict__ f, const float* __restrict__ gamma,
               const float* __restrict__ beta, float* __restrict__ xnorm) {
  int p = blockIdx.x * 256 + threadIdx.x;        // one (b,t,q) per thread
  int q = p & (QQ - 1);
  int t = (p >> 7) & (TT - 1);
  int b = p >> 14;
  const float* base = f + (size_t)b * CC * TT * QQ + (size_t)t * QQ + q;
  float s = 0.f, s2 = 0.f;
  for (int c = 0; c < CC; ++c) {
    float v = base[(size_t)c * TT * QQ];
    s += v; s2 += v * v;
  }
  float mu = s * (1.f / CC);
  float var = s2 * (1.f / CC) - mu * mu;
  float rs = rsqrtf(var + 1e-5f);
  int n = b * TT + t;
  float* o = xnorm + (size_t)n * CC * QQ + q;    // [n][c][q]
  for (int c = 0; c < CC; ++c) {
    float v = base[(size_t)c * TT * QQ];
    o[(size_t)c * QQ] = (v - mu) * rs * gamma[c] + beta[c];
  }
}

// ------------- rearrange ct_w [2H][C][K] -> Bc[d=(k*256+j)][c] -------------
__global__ __launch_bounds__(256)
void prep_bconv(const float* __restrict__ ctw, float* __restrict__ Bc) {
  int idx = blockIdx.x * 256 + threadIdx.x;      // 2048*64 total
  if (idx >= 2048 * 64) return;
  int c = idx & 63;
  int d = idx >> 6;
  int k = d >> 8, j = d & 255;
  Bc[idx] = ctw[(size_t)j * (CC * KK) + c * KK + k];
}

// ---------------- main SRU-input GEMM: U[n][l][4H] = seq @ W ----------------
// A[l][d] with d = c*8+k  ==  xnorm[n][c][l+k]   (unfold gathered on load)
__global__ __launch_bounds__(256)
void gemm_kernel(const float* __restrict__ xnorm, const float* __restrict__ W,
                 float* __restrict__ U, int n0) {
  __shared__ float As_T[32][68];   // [dd][row], padded, 16B-aligned rows
  __shared__ float Bs[32][68];     // [dd][col]
  int n  = n0 + blockIdx.z;
  int l0 = blockIdx.y * 64;
  int j0 = blockIdx.x * 64;
  int tid = threadIdx.x;
  int arow = tid >> 2, acol0 = (tid & 3) * 8;    // A stage: 8 elems, k=0..7
  int brow = tid >> 3, bcol0 = (tid & 7) * 8;    // B stage: 8 contiguous cols
  int tx = tid & 15, ty = tid >> 4;
  const float* xb = xnorm + (size_t)n * CC * QQ;
  float acc[4][4] = {};
  for (int d0 = 0; d0 < DIN; d0 += 32) {
    int l = l0 + arow;
    {
      int c = (d0 + acol0) >> 3;                 // fixed over i; k == i
      const float* src = xb + (size_t)c * QQ + l;
      bool ok = (l < LL);
#pragma unroll
      for (int i = 0; i < 8; ++i)
        As_T[acol0 + i][arow] = ok ? src[i] : 0.f;
    }
    {
      const float4* w4 = reinterpret_cast<const float4*>(
          W + (size_t)(d0 + brow) * FOURH + j0 + bcol0);
      float4 wa = w4[0], wb = w4[1];
      Bs[brow][bcol0 + 0] = wa.x; Bs[brow][bcol0 + 1] = wa.y;
      Bs[brow][bcol0 + 2] = wa.z; Bs[brow][bcol0 + 3] = wa.w;
      Bs[brow][bcol0 + 4] = wb.x; Bs[brow][bcol0 + 5] = wb.y;
      Bs[brow][bcol0 + 6] = wb.z; Bs[brow][bcol0 + 7] = wb.w;
    }
    __syncthreads();
#pragma unroll
    for (int dd = 0; dd < 32; ++dd) {
      float4 a4 = *reinterpret_cast<const float4*>(&As_T[dd][ty * 4]);
      float4 b4 = *reinterpret_cast<const float4*>(&Bs[dd][tx * 4]);
      float a[4] = {a4.x, a4.y, a4.z, a4.w};
      float bb[4] = {b4.x, b4.y, b4.z, b4.w};
#pragma unroll
      for (int i = 0; i < 4; ++i)
#pragma unroll
        for (int j = 0; j < 4; ++j) acc[i][j] += a[i] * bb[j];
    }
    __syncthreads();
  }
  int nl = blockIdx.z;
#pragma unroll
  for (int i = 0; i < 4; ++i) {
    int l = l0 + ty * 4 + i;
    if (l < LL) {
      float* dst = U + ((size_t)nl * LL + l) * FOURH + j0 + tx * 4;
#pragma unroll
      for (int j = 0; j < 4; ++j) dst[j] = acc[i][j];
    }
  }
}

// ---------------- zero the pad rows of hpad ----------------
__global__ __launch_bounds__(256)
void pad_kernel(float* __restrict__ hp) {
  int nl = blockIdx.x, tid = threadIdx.x;
  float* base = hp + (size_t)nl * LPAD * TWOH;
#pragma unroll
  for (int r = 0; r < 7; ++r) base[(size_t)r * TWOH + tid] = 0.f;
#pragma unroll
  for (int r = 128; r < 135; ++r) base[(size_t)r * TWOH + tid] = 0.f;
}

// ---------------- SRU recurrence (both directions) ----------------
__global__ __launch_bounds__(256)
void scan_kernel(const float* __restrict__ Uf, const float* __restrict__ Ub,
                 const float* __restrict__ bfwd, const float* __restrict__ bbwd,
                 float* __restrict__ hp, int nCount) {
  int tid = blockIdx.x * 256 + threadIdx.x;
  if (tid >= nCount * 256) return;
  int h   = tid & (HH - 1);
  int dir = (tid >> 7) & 1;                      // wave-uniform
  int nl  = tid >> 8;
  const float* U    = dir ? Ub : Uf;
  const float* bias = dir ? bbwd : bfwd;
  float bf = bias[h], br = bias[HH + h];
  const float* Ubase = U + (size_t)nl * LL * FOURH + h;
  float* hb = hp + (size_t)nl * LPAD * TWOH + dir * HH + h;
  float cacc = 0.f;
  if (dir == 0) {
    float xt = Ubase[0], fp = Ubase[HH], rp = Ubase[2 * HH], xp = Ubase[3 * HH];
    for (int l = 0; l < LL; ++l) {
      float nxt = 0.f, nfp = 0.f, nrp = 0.f, nxp = 0.f;
      if (l + 1 < LL) {
        const float* nb = Ubase + (size_t)(l + 1) * FOURH;
        nxt = nb[0]; nfp = nb[HH]; nrp = nb[2 * HH]; nxp = nb[3 * HH];
      }
      float fg = 1.f / (1.f + __expf(-(fp + bf)));
      float rg = 1.f / (1.f + __expf(-(rp + br)));
      cacc = fg * cacc + (1.f - fg) * xt;
      float e2 = __expf(2.f * cacc);
      float th = (e2 - 1.f) / (e2 + 1.f);
      hb[(size_t)(l + 7) * TWOH] = rg * th + (1.f - rg) * xp;
      xt = nxt; fp = nfp; rp = nrp; xp = nxp;
    }
  } else {
    const float* s0 = Ubase + (size_t)(LL - 1) * FOURH;
    float xt = s0[0], fp = s0[HH], rp = s0[2 * HH], xp = s0[3 * HH];
    for (int l = LL - 1; l >= 0; --l) {
      float nxt = 0.f, nfp = 0.f, nrp = 0.f, nxp = 0.f;
      if (l - 1 >= 0) {
        const float* nb = Ubase + (size_t)(l - 1) * FOURH;
        nxt = nb[0]; nfp = nb[HH]; nrp = nb[2 * HH]; nxp = nb[3 * HH];
      }
      float fg = 1.f / (1.f + __expf(-(fp + bf)));
      float rg = 1.f / (1.f + __expf(-(rp + br)));
      cacc = fg * cacc + (1.f - fg) * xt;
      float e2 = __expf(2.f * cacc);
      float th = (e2 - 1.f) / (e2 + 1.f);
      hb[(size_t)(l + 7) * TWOH] = rg * th + (1.f - rg) * xp;
      xt = nxt; fp = nfp; rp = nrp; xp = nxp;
    }
  }
}

// ------------- ConvTranspose as GEMM: out[(n,q)][c] over d=(k,j), 2048 -------------
// A[q][d] = hpad[n][q-k+7][j]  (pad rows are zero -> no bounds checks)
__global__ __launch_bounds__(256)
void conv_kernel(const float* __restrict__ hp, const float* __restrict__ Bc,
                 const float* __restrict__ ctb, const float* __restrict__ feat,
                 float* __restrict__ out, int n0) {
  __shared__ float As_T[32][68];
  __shared__ float Bs[32][68];
  int nl = blockIdx.z;
  int n  = n0 + nl;
  int q0 = blockIdx.y * 64;
  int tid = threadIdx.x;
  int arow = tid >> 2, acol0 = (tid & 3) * 8;
  int brow = tid >> 3, bcol0 = (tid & 7) * 8;
  int tx = tid & 15, ty = tid >> 4;
  const float* hbase = hp + (size_t)nl * LPAD * TWOH;
  float acc[4][4] = {};
  for (int d0 = 0; d0 < 2048; d0 += 32) {
    {
      int d = d0 + acol0;
      int k = d >> 8, j = d & 255;               // fixed over i (32-step within k-block)
      int row = q0 + arow - k + 7;               // always within [0,134]
      const float4* src = reinterpret_cast<const float4*>(
          hbase + (size_t)row * TWOH + j);
      float4 v0 = src[0], v1 = src[1];
      As_T[acol0 + 0][arow] = v0.x; As_T[acol0 + 1][arow] = v0.y;
      As_T[acol0 + 2][arow] = v0.z; As_T[acol0 + 3][arow] = v0.w;
      As_T[acol0 + 4][arow] = v1.x; As_T[acol0 + 5][arow] = v1.y;
      As_T[acol0 + 6][arow] = v1.z; As_T[acol0 + 7][arow] = v1.w;
    }
    {
      const float4* b4p = reinterpret_cast<const float4*>(
          Bc + (size_t)(d0 + brow) * 64 + bcol0);
      float4 wa = b4p[0], wb = b4p[1];
      Bs[brow][bcol0 + 0] = wa.x; Bs[brow][bcol0 + 1] = wa.y;
      Bs[brow][bcol0 + 2] = wa.z; Bs[brow][bcol0 + 3] = wa.w;
      Bs[brow][bcol0 + 4] = wb.x; Bs[brow][bcol0 + 5] = wb.y;
      Bs[brow][bcol0 + 6] = wb.z; Bs[brow][bcol0 + 7] = wb.w;
    }
    __syncthreads();
#pragma unroll
    for (int dd = 0; dd < 32; ++dd) {
      float4 a4 = *reinterpret_cast<const float4*>(&As_T[dd][ty * 4]);
      float4 b4 = *reinterpret_cast<const float4*>(&Bs[dd][tx * 4]);
      float a[4] = {a4.x, a4.y, a4.z, a4.w};
      float bb[4] = {b4.x, b4.y, b4.z, b4.w};
#pragma unroll
      for (int i = 0; i < 4; ++i)
#pragma unroll
        for (int j = 0; j < 4; ++j) acc[i][j] += a[i] * bb[j];
    }
    __syncthreads();
  }
  int b = n >> 7, t = n & 127;
#pragma unroll
  for (int i = 0; i < 4; ++i) {
    int q = q0 + ty * 4 + i;
#pragma unroll
    for (int jj = 0; jj < 4; ++jj) {
      int c = tx * 4 + jj;
      size_t oidx = (size_t)b * (CC * TT * QQ) + (size_t)c * (TT * QQ)
                  + (size_t)t * QQ + q;
      out[oidx] = acc[i][jj] + ctb[c] + feat[oidx];
    }
  }
}

extern "C" void kernel_launch(void* const* d_in, const int* in_sizes, int n_in,
                              void* d_out, int out_size, void* d_ws, size_t ws_size,
                              hipStream_t stream) {
  const float* feat  = (const float*)d_in[0];
  const float* gamma = (const float*)d_in[1];
  const float* beta  = (const float*)d_in[2];
  const float* w_fwd = (const float*)d_in[3];
  const float* b_fwd = (const float*)d_in[4];
  const float* w_bwd = (const float*)d_in[5];
  const float* b_bwd = (const float*)d_in[6];
  const float* ct_w  = (const float*)d_in[7];
  const float* ct_b  = (const float*)d_in[8];
  float* out = (float*)d_out;
  float* ws  = (float*)d_ws;

  float* xnorm = ws;
  size_t off = (size_t)NN * CC * QQ;          // 4,194,304 floats
  float* Bc = ws + off;
  off += 2048 * 64;                           // +131,072 floats

  // choose chunk size NC over n based on available workspace
  size_t avail = ws_size / 4;
  size_t per_n = 2 * (size_t)LL * FOURH + (size_t)LPAD * TWOH;  // 158,464 floats
  int NC = 4;
  for (int cand = 512; cand >= 4; cand >>= 1) {
    if (off + (size_t)cand * per_n <= avail) { NC = cand; break; }
  }
  float* Uf = ws + off;
  float* Ub = Uf + (size_t)NC * LL * FOURH;
  float* hp = Ub + (size_t)NC * LL * FOURH;

  ln_kernel<<<dim3(256), dim3(256), 0, stream>>>(feat, gamma, beta, xnorm);
  prep_bconv<<<dim3(512), dim3(256), 0, stream>>>(ct_w, Bc);

  for (int n0 = 0; n0 < NN; n0 += NC) {
    dim3 gg(FOURH / 64, 2, NC);
    gemm_kernel<<<gg, dim3(256), 0, stream>>>(xnorm, w_fwd, Uf, n0);
    gemm_kernel<<<gg, dim3(256), 0, stream>>>(xnorm, w_bwd, Ub, n0);
    pad_kernel<<<dim3(NC), dim3(256), 0, stream>>>(hp);
    scan_kernel<<<dim3(NC), dim3(256), 0, stream>>>(Uf, Ub, b_fwd, b_bwd, hp, NC);
    conv_kernel<<<dim3(1, 2, NC), dim3(256), 0, stream>>>(hp, Bc, ct_b, feat, out, n0);
  }
}

// Round 2
// 312.881 us; speedup vs baseline: 4.6043x; 4.6043x over previous
//
#include <hip/hip_runtime.h>
#include <math.h>

#define BB 4
#define CC 64
#define TT 128
#define QQ 128
#define KK 8
#define HH 128
#define NN 512
#define LL 121
#define LPAD 135

typedef unsigned short ushort;
typedef __attribute__((ext_vector_type(8))) short short8;
typedef __attribute__((ext_vector_type(4))) float f32x4;
typedef __attribute__((ext_vector_type(4))) float float4v;

#define GLP(p) ((const __attribute__((address_space(1))) void*)(p))
#define LDP(p) ((__attribute__((address_space(3))) void*)(p))

__device__ __forceinline__ ushort f2bf(float x) {
  unsigned u = __float_as_uint(x);
  unsigned r = (u + 0x7FFFu + ((u >> 16) & 1u)) >> 16;
  return (ushort)r;
}
__device__ __forceinline__ float bf2f(ushort x) {
  return __uint_as_float(((unsigned)x) << 16);
}

// ---------------- LayerNorm over channel dim -> bf16 xbf[n][c][q] ----------------
__global__ __launch_bounds__(256)
void ln_kernel(const float* __restrict__ f, const float* __restrict__ gamma,
               const float* __restrict__ beta, ushort* __restrict__ xbf) {
  int p = blockIdx.x * 256 + threadIdx.x;
  int q = p & (QQ - 1);
  int t = (p >> 7) & (TT - 1);
  int b = p >> 14;
  const float* base = f + (size_t)b * CC * TT * QQ + (size_t)t * QQ + q;
  float s = 0.f, s2 = 0.f;
  for (int c = 0; c < CC; ++c) {
    float v = base[(size_t)c * TT * QQ];
    s += v; s2 += v * v;
  }
  float mu = s * (1.f / CC);
  float var = s2 * (1.f / CC) - mu * mu;
  float rs = rsqrtf(var + 1e-5f);
  int n = b * TT + t;
  ushort* o = xbf + (size_t)n * CC * QQ + q;
  for (int c = 0; c < CC; ++c) {
    float v = base[(size_t)c * TT * QQ];
    o[(size_t)c * QQ] = f2bf((v - mu) * rs * gamma[c] + beta[c]);
  }
}

// ------- Wt[j][k] = W_cat[k][j] bf16; j<512 -> w_fwd, else w_bwd (1024x512) -------
__global__ __launch_bounds__(256)
void prep_w(const float* __restrict__ wf, const float* __restrict__ wb,
            ushort* __restrict__ Wt) {
  int idx = blockIdx.x * 256 + threadIdx.x;      // 1024*512
  int j = idx >> 9, k = idx & 511;
  const float* w = (j < 512) ? wf : wb;
  int jj = j & 511;
  Wt[idx] = f2bf(w[(size_t)k * 512 + jj]);
}

// ------- Bct[c][k*256+j] = ct_w[j][c][k] bf16 (64 x 2048) -------
__global__ __launch_bounds__(256)
void prep_bc(const float* __restrict__ ctw, ushort* __restrict__ Bct) {
  int idx = blockIdx.x * 256 + threadIdx.x;      // 64*2048
  int c = idx >> 11, d = idx & 2047;
  int k = d >> 8, j = d & 255;
  Bct[idx] = f2bf(ctw[(size_t)j * (CC * KK) + c * KK + k]);
}

// ------- unfold: Abf[n][l][c*8+k] = xbf[n][c][l+k], zero rows l>=121 -------
__global__ __launch_bounds__(256)
void unfold_k(const ushort* __restrict__ xbf, ushort* __restrict__ Abf, int n0) {
  __shared__ ushort lx[64 * 130];
  int nl = blockIdx.x, tid = threadIdx.x;
  const ushort* src = xbf + (size_t)(n0 + nl) * (CC * QQ);
#pragma unroll
  for (int i = 0; i < 4; ++i) {
    int e = (i * 256 + tid) * 8;
    short8 v = *(const short8*)&src[e];
    int c = e >> 7, q0 = e & 127;
#pragma unroll
    for (int k = 0; k < 8; ++k) lx[c * 130 + q0 + k] = (ushort)v[k];
  }
  __syncthreads();
  ushort* dst = Abf + (size_t)nl * 128 * 512;
  for (int it = 0; it < 32; ++it) {
    int idx = it * 256 + tid;
    int c8 = idx & 63, l = idx >> 6;
    short8 ov;
    if (l <= 120) {
#pragma unroll
      for (int k = 0; k < 8; ++k) ov[k] = (short)lx[c8 * 130 + l + k];
    } else {
#pragma unroll
      for (int k = 0; k < 8; ++k) ov[k] = 0;
    }
    *(short8*)&dst[(size_t)l * 512 + c8 * 8] = ov;
  }
}

// ---------------- fused MFMA GEMM: U[M=NC*128][1024] = Abf @ Wt^T ----------------
__global__ __launch_bounds__(256)
void gemm_mfma(const ushort* __restrict__ Abf, const ushort* __restrict__ Wt,
               float* __restrict__ U) {
  __shared__ ushort As[128 * 64];
  __shared__ ushort Bs[128 * 64];
  int tid = threadIdx.x;
  int nl = blockIdx.y;
  int j0 = blockIdx.x * 128;
  int lane = tid & 63, w = tid >> 6;
  int wr0 = (w >> 1) * 64, wc0 = (w & 1) * 64;
  int lrow = lane & 15, lk = lane >> 4;
  f32x4 acc[4][4] = {};
  const ushort* Ab = Abf + (size_t)nl * 128 * 512;
  for (int ks = 0; ks < 8; ++ks) {
    int k0 = ks * 64;
    if (ks) __syncthreads();
#pragma unroll
    for (int i = 0; i < 4; ++i) {
      int p = i * 256 + tid;
      int row = p >> 3, s = (p & 7) ^ (row & 7);
      const ushort* g = Ab + (size_t)row * 512 + k0 + s * 8;
      ushort* l = &As[(size_t)(i * 256 + (tid & 192)) * 8];
      __builtin_amdgcn_global_load_lds(GLP(g), LDP(l), 16, 0, 0);
    }
#pragma unroll
    for (int i = 0; i < 4; ++i) {
      int p = i * 256 + tid;
      int row = p >> 3, s = (p & 7) ^ (row & 7);
      const ushort* g = Wt + (size_t)(j0 + row) * 512 + k0 + s * 8;
      ushort* l = &Bs[(size_t)(i * 256 + (tid & 192)) * 8];
      __builtin_amdgcn_global_load_lds(GLP(g), LDP(l), 16, 0, 0);
    }
    __syncthreads();
#pragma unroll
    for (int s = 0; s < 2; ++s) {
      short8 a[4], b[4];
#pragma unroll
      for (int m = 0; m < 4; ++m) {
        int r = wr0 + m * 16 + lrow;
        int slot = (s * 4 + lk) ^ (r & 7);
        a[m] = *(const short8*)&As[r * 64 + slot * 8];
      }
#pragma unroll
      for (int nn = 0; nn < 4; ++nn) {
        int j = wc0 + nn * 16 + lrow;
        int slot = (s * 4 + lk) ^ (j & 7);
        b[nn] = *(const short8*)&Bs[j * 64 + slot * 8];
      }
#pragma unroll
      for (int m = 0; m < 4; ++m)
#pragma unroll
        for (int nn = 0; nn < 4; ++nn)
          acc[m][nn] = __builtin_amdgcn_mfma_f32_16x16x32_bf16(
              a[m], b[nn], acc[m][nn], 0, 0, 0);
    }
  }
  float* Urow = U + (size_t)nl * 128 * 1024 + j0;
#pragma unroll
  for (int m = 0; m < 4; ++m) {
#pragma unroll
    for (int g = 0; g < 4; ++g) {
      int r = wr0 + m * 16 + lk * 4 + g;
#pragma unroll
      for (int nn = 0; nn < 4; ++nn) {
        int j = wc0 + nn * 16 + lrow;
        Urow[(size_t)r * 1024 + j] = acc[m][nn][g];
      }
    }
  }
}

// ---------------- SRU recurrence; writes bf16 hp and zeroes pads ----------------
__global__ __launch_bounds__(256)
void scan_kernel(const float* __restrict__ U, const float* __restrict__ bfwd,
                 const float* __restrict__ bbwd, ushort* __restrict__ hp) {
  int nl = blockIdx.x, tid = threadIdx.x;
  int h = tid & 127, dir = tid >> 7;
  ushort* hpn = hp + (size_t)nl * LPAD * 256;
  // zero pad rows
#pragma unroll
  for (int r = 0; r < 7; ++r) hpn[(size_t)r * 256 + tid] = 0;
#pragma unroll
  for (int r = 128; r < 135; ++r) hpn[(size_t)r * 256 + tid] = 0;
  const float* bias = dir ? bbwd : bfwd;
  float bf = bias[h], br = bias[HH + h];
  const float* Ub = U + (size_t)nl * 128 * 1024 + dir * 512 + h;
  ushort* hb = hpn + dir * HH + h;
  float cacc = 0.f;
  if (dir == 0) {
    for (int l = 0; l < LL; ++l) {
      const float* row = Ub + (size_t)l * 1024;
      float xt = row[0], fp = row[128], rp = row[256], xp = row[384];
      float fg = 1.f / (1.f + __expf(-(fp + bf)));
      float rg = 1.f / (1.f + __expf(-(rp + br)));
      cacc = fg * cacc + (1.f - fg) * xt;
      float e2 = __expf(2.f * cacc);
      float th = (e2 - 1.f) / (e2 + 1.f);
      hb[(size_t)(l + 7) * 256] = f2bf(rg * th + (1.f - rg) * xp);
    }
  } else {
    for (int l = LL - 1; l >= 0; --l) {
      const float* row = Ub + (size_t)l * 1024;
      float xt = row[0], fp = row[128], rp = row[256], xp = row[384];
      float fg = 1.f / (1.f + __expf(-(fp + bf)));
      float rg = 1.f / (1.f + __expf(-(rp + br)));
      cacc = fg * cacc + (1.f - fg) * xt;
      float e2 = __expf(2.f * cacc);
      float th = (e2 - 1.f) / (e2 + 1.f);
      hb[(size_t)(l + 7) * 256] = f2bf(rg * th + (1.f - rg) * xp);
    }
  }
}

// ---------------- ConvTranspose as MFMA GEMM ----------------
// out[(n,q)][c] = sum_{d=k*256+j} hp[n][q-k+7][j] * Bct[c][d]; + ctb + feat
__global__ __launch_bounds__(256)
void conv_mfma(const ushort* __restrict__ hp, const ushort* __restrict__ Bct,
               const float* __restrict__ ctb, const float* __restrict__ feat,
               float* __restrict__ out, int n0) {
  __shared__ ushort As[128 * 64];
  __shared__ ushort Bs[64 * 64];
  int tid = threadIdx.x;
  int nl = blockIdx.x;
  int lane = tid & 63, w = tid >> 6;
  int wr0 = (w >> 1) * 64, wc0 = (w & 1) * 32;
  int lrow = lane & 15, lk = lane >> 4;
  f32x4 acc[4][2] = {};
  const ushort* hpn = hp + (size_t)nl * LPAD * 256;
  for (int ks = 0; ks < 32; ++ks) {
    int d0 = ks * 64;
    int kk = d0 >> 8, j0 = d0 & 255;
    if (ks) __syncthreads();
#pragma unroll
    for (int i = 0; i < 4; ++i) {   // A: 128x64 = 1024 slots
      int p = i * 256 + tid;
      int row = p >> 3, s = (p & 7) ^ (row & 7);
      const ushort* g = hpn + (size_t)(row - kk + 7) * 256 + j0 + s * 8;
      ushort* l = &As[(size_t)(i * 256 + (tid & 192)) * 8];
      __builtin_amdgcn_global_load_lds(GLP(g), LDP(l), 16, 0, 0);
    }
#pragma unroll
    for (int i = 0; i < 2; ++i) {   // B: 64x64 = 512 slots
      int p = i * 256 + tid;
      int row = p >> 3, s = (p & 7) ^ (row & 7);
      const ushort* g = Bct + (size_t)row * 2048 + d0 + s * 8;
      ushort* l = &Bs[(size_t)(i * 256 + (tid & 192)) * 8];
      __builtin_amdgcn_global_load_lds(GLP(g), LDP(l), 16, 0, 0);
    }
    __syncthreads();
#pragma unroll
    for (int s = 0; s < 2; ++s) {
      short8 a[4], b[2];
#pragma unroll
      for (int m = 0; m < 4; ++m) {
        int r = wr0 + m * 16 + lrow;
        int slot = (s * 4 + lk) ^ (r & 7);
        a[m] = *(const short8*)&As[r * 64 + slot * 8];
      }
#pragma unroll
      for (int nn = 0; nn < 2; ++nn) {
        int c = wc0 + nn * 16 + lrow;
        int slot = (s * 4 + lk) ^ (c & 7);
        b[nn] = *(const short8*)&Bs[c * 64 + slot * 8];
      }
#pragma unroll
      for (int m = 0; m < 4; ++m)
#pragma unroll
        for (int nn = 0; nn < 2; ++nn)
          acc[m][nn] = __builtin_amdgcn_mfma_f32_16x16x32_bf16(
              a[m], b[nn], acc[m][nn], 0, 0, 0);
    }
  }
  int n = n0 + nl;
  int b = n >> 7, t = n & 127;
#pragma unroll
  for (int m = 0; m < 4; ++m) {
    int q0 = wr0 + m * 16 + lk * 4;
#pragma unroll
    for (int nn = 0; nn < 2; ++nn) {
      int c = wc0 + nn * 16 + lrow;
      size_t idx = (size_t)b * (CC * TT * QQ) + (size_t)c * (TT * QQ)
                 + (size_t)t * QQ + q0;
      float4v fv = *(const float4v*)&feat[idx];
      float cb = ctb[c];
      float4v ov;
#pragma unroll
      for (int g = 0; g < 4; ++g) ov[g] = acc[m][nn][g] + cb + fv[g];
      *(float4v*)&out[idx] = ov;
    }
  }
}

extern "C" void kernel_launch(void* const* d_in, const int* in_sizes, int n_in,
                              void* d_out, int out_size, void* d_ws, size_t ws_size,
                              hipStream_t stream) {
  const float* feat  = (const float*)d_in[0];
  const float* gamma = (const float*)d_in[1];
  const float* beta  = (const float*)d_in[2];
  const float* w_fwd = (const float*)d_in[3];
  const float* b_fwd = (const float*)d_in[4];
  const float* w_bwd = (const float*)d_in[5];
  const float* b_bwd = (const float*)d_in[6];
  const float* ct_w  = (const float*)d_in[7];
  const float* ct_b  = (const float*)d_in[8];
  float* out = (float*)d_out;

  char* wsb = (char*)d_ws;
  ushort* xbf = (ushort*)wsb;                         // 512*64*128*2 = 8,388,608
  ushort* Wt  = (ushort*)(wsb + 8388608);             // 1024*512*2  = 1,048,576
  ushort* Bct = (ushort*)(wsb + 9437184);             // 64*2048*2   =   262,144
  size_t persist = 9699328;
  size_t per_n = 131072u /*Abf*/ + 524288u /*U*/ + 69120u /*hp*/;
  int NC = 4;
  for (int cand = 512; cand >= 4; cand >>= 1) {
    if (persist + (size_t)cand * per_n <= ws_size) { NC = cand; break; }
  }
  char* dyn = wsb + persist;
  ushort* Abf = (ushort*)dyn;
  float*  Uc  = (float*)(dyn + (size_t)NC * 131072u);
  ushort* hpc = (ushort*)(dyn + (size_t)NC * 131072u + (size_t)NC * 524288u);

  ln_kernel<<<dim3(256), dim3(256), 0, stream>>>(feat, gamma, beta, xbf);
  prep_w<<<dim3(2048), dim3(256), 0, stream>>>(w_fwd, w_bwd, Wt);
  prep_bc<<<dim3(512), dim3(256), 0, stream>>>(ct_w, Bct);

  for (int n0 = 0; n0 < NN; n0 += NC) {
    unfold_k<<<dim3(NC), dim3(256), 0, stream>>>(xbf, Abf, n0);
    gemm_mfma<<<dim3(8, NC), dim3(256), 0, stream>>>(Abf, Wt, Uc);
    scan_kernel<<<dim3(NC), dim3(256), 0, stream>>>(Uc, b_fwd, b_bwd, hpc);
    conv_mfma<<<dim3(NC), dim3(256), 0, stream>>>(hpc, Bct, ct_b, feat, out, n0);
  }
}

// Round 3
// 183.566 us; speedup vs baseline: 7.8478x; 1.7045x over previous
//
#include <hip/hip_runtime.h>
#include <math.h>

#define BB 4
#define CC 64
#define TT 128
#define QQ 128
#define KK 8
#define HH 128
#define NN 512
#define LL 121
#define LPAD 135

typedef unsigned short ushort;
typedef __attribute__((ext_vector_type(8))) short short8;
typedef __attribute__((ext_vector_type(4))) float f32x4;
typedef __attribute__((ext_vector_type(4))) float float4v;
typedef _Float16 __attribute__((ext_vector_type(4))) half4;

#define GLP(p) ((const __attribute__((address_space(1))) void*)(p))
#define LDP(p) ((__attribute__((address_space(3))) void*)(p))

__device__ __forceinline__ ushort f2bf(float x) {
  unsigned u = __float_as_uint(x);
  unsigned r = (u + 0x7FFFu + ((u >> 16) & 1u)) >> 16;
  return (ushort)r;
}

// ---------- LayerNorm over channel dim -> TRANSPOSED bf16 xT[n][q][c] ----------
__global__ __launch_bounds__(256)
void ln_kernel(const float* __restrict__ f, const float* __restrict__ gamma,
               const float* __restrict__ beta, ushort* __restrict__ xT) {
  int p = blockIdx.x * 256 + threadIdx.x;
  int q = p & (QQ - 1);
  int t = (p >> 7) & (TT - 1);
  int b = p >> 14;
  const float* base = f + (size_t)b * CC * TT * QQ + (size_t)t * QQ + q;
  float s = 0.f, s2 = 0.f;
  for (int c = 0; c < CC; ++c) {
    float v = base[(size_t)c * TT * QQ];
    s += v; s2 += v * v;
  }
  float mu = s * (1.f / CC);
  float var = s2 * (1.f / CC) - mu * mu;
  float rs = rsqrtf(var + 1e-5f);
  int n = b * TT + t;
  ushort* dst = xT + (size_t)n * (CC * QQ) + (size_t)q * CC;
#pragma unroll
  for (int v8 = 0; v8 < 8; ++v8) {
    short8 ov;
#pragma unroll
    for (int e = 0; e < 8; ++e) {
      int c = v8 * 8 + e;
      float v = base[(size_t)c * TT * QQ];
      ov[e] = (short)f2bf((v - mu) * rs * gamma[c] + beta[c]);
    }
    *(short8*)(dst + v8 * 8) = ov;
  }
}

// ---- Wt[r][d], d = k*64+c (k-major); r permuted h-major-within-pairs ----
// r -> dir=r>>9, t=r&511, h=(t>>7)*32+((t>>6)&1)*16+(t&15), quad=(t>>4)&3
__global__ __launch_bounds__(256)
void prep_w(const float* __restrict__ wf, const float* __restrict__ wb,
            ushort* __restrict__ Wt) {
  int idx = blockIdx.x * 256 + threadIdx.x;      // 1024*512
  int r = idx >> 9, d = idx & 511;
  int k = d >> 6, c = d & 63;
  int dir = r >> 9, t = r & 511;
  int h = (t >> 7) * 32 + ((t >> 6) & 1) * 16 + (t & 15);
  int quad = (t >> 4) & 3;
  const float* w = dir ? wb : wf;
  Wt[idx] = f2bf(w[(size_t)(c * 8 + k) * 512 + quad * 128 + h]);
}

// ------- Bct[c][k*256+j] = ct_w[j][c][k] bf16 (64 x 2048) -------
__global__ __launch_bounds__(256)
void prep_bc(const float* __restrict__ ctw, ushort* __restrict__ Bct) {
  int idx = blockIdx.x * 256 + threadIdx.x;      // 64*2048
  int c = idx >> 11, d = idx & 2047;
  int k = d >> 8, j = d & 255;
  Bct[idx] = f2bf(ctw[(size_t)j * (CC * KK) + c * KK + k]);
}

// ---------------- fused MFMA GEMM + unfold + gate epilogue ----------------
// U[l][r] = sum_d A[l][d] * Wt[r][d];  A[l][k*64+c] = xT[n][l+k][c]
__global__ __launch_bounds__(256)
void gemm_mfma(const ushort* __restrict__ xT, const ushort* __restrict__ Wt,
               const float* __restrict__ b_fwd, const float* __restrict__ b_bwd,
               half4* __restrict__ scanU, int n0) {
  __shared__ ushort As[128 * 64];
  __shared__ ushort Bs[128 * 64];
  int tid = threadIdx.x;
  int nl = blockIdx.y;
  int r0 = blockIdx.x * 128;
  int lane = tid & 63, w = tid >> 6;
  int wr0 = (w >> 1) * 64, wc0 = (w & 1) * 64;
  int lrow = lane & 15, lk = lane >> 4;
  f32x4 acc[4][4] = {};
  const ushort* xTn = xT + (size_t)(n0 + nl) * (CC * QQ);
  for (int ks = 0; ks < 8; ++ks) {
    if (ks) __syncthreads();
#pragma unroll
    for (int i = 0; i < 4; ++i) {            // A: gather-unfold from xT
      int p = i * 256 + tid;
      int row = p >> 3, s = (p & 7) ^ (row & 7);
      const ushort* g = xTn + (size_t)(row + ks) * CC + s * 8;
      ushort* l = &As[(size_t)(i * 256 + (tid & 192)) * 8];
      __builtin_amdgcn_global_load_lds(GLP(g), LDP(l), 16, 0, 0);
    }
#pragma unroll
    for (int i = 0; i < 4; ++i) {            // B
      int p = i * 256 + tid;
      int row = p >> 3, s = (p & 7) ^ (row & 7);
      const ushort* g = Wt + (size_t)(r0 + row) * 512 + ks * 64 + s * 8;
      ushort* l = &Bs[(size_t)(i * 256 + (tid & 192)) * 8];
      __builtin_amdgcn_global_load_lds(GLP(g), LDP(l), 16, 0, 0);
    }
    __syncthreads();
#pragma unroll
    for (int s = 0; s < 2; ++s) {
      short8 a[4], b[4];
#pragma unroll
      for (int m = 0; m < 4; ++m) {
        int r = wr0 + m * 16 + lrow;
        int slot = (s * 4 + lk) ^ (r & 7);
        a[m] = *(const short8*)&As[r * 64 + slot * 8];
      }
#pragma unroll
      for (int nn = 0; nn < 4; ++nn) {
        int j = wc0 + nn * 16 + lrow;
        int slot = (s * 4 + lk) ^ (j & 7);
        b[nn] = *(const short8*)&Bs[j * 64 + slot * 8];
      }
#pragma unroll
      for (int m = 0; m < 4; ++m)
#pragma unroll
        for (int nn = 0; nn < 4; ++nn)
          acc[m][nn] = __builtin_amdgcn_mfma_f32_16x16x32_bf16(
              a[m], b[nn], acc[m][nn], 0, 0, 0);
    }
  }
  // epilogue: thread holds all 4 quadrants (nn) of one h for 16 rows
  int dir = r0 >> 9;
  int h = ((r0 & 511) >> 7) * 32 + (wc0 >> 6) * 16 + lrow;
  const float* bias = dir ? b_bwd : b_fwd;
  float bf = bias[h], br = bias[128 + h];
#pragma unroll
  for (int m = 0; m < 4; ++m) {
#pragma unroll
    for (int g = 0; g < 4; ++g) {
      int l = wr0 + m * 16 + lk * 4 + g;
      float xt = acc[m][0][g], fp = acc[m][1][g];
      float rp = acc[m][2][g], xp = acc[m][3][g];
      float fg = 1.f / (1.f + __expf(-(fp + bf)));
      float rg = 1.f / (1.f + __expf(-(rp + br)));
      float u = (1.f - fg) * xt;
      half4 qv = {(_Float16)u, (_Float16)fg, (_Float16)rg, (_Float16)xp};
      scanU[((size_t)(nl * 128 + l) * 2 + dir) * 128 + h] = qv;
    }
  }
}

// ---------------- SRU recurrence from fp16 quads; writes bf16 hp ----------------
__global__ __launch_bounds__(256)
void scan_kernel(const half4* __restrict__ scanU, ushort* __restrict__ hp) {
  int nl = blockIdx.x, tid = threadIdx.x;
  int h = tid & 127, dir = tid >> 7;
  ushort* hpn = hp + (size_t)nl * LPAD * 256;
#pragma unroll
  for (int r = 0; r < 7; ++r) hpn[(size_t)r * 256 + tid] = 0;
#pragma unroll
  for (int r = 128; r < 135; ++r) hpn[(size_t)r * 256 + tid] = 0;
  const half4* Ub = scanU + ((size_t)nl * 128 * 2 + dir) * 128 + h;
  ushort* hb = hpn + dir * HH + h;
  float cacc = 0.f;
  if (dir == 0) {
    for (int l = 0; l < LL; ++l) {
      half4 v = Ub[(size_t)l * 256];
      float u = (float)v[0], fg = (float)v[1], rg = (float)v[2], xp = (float)v[3];
      cacc = fg * cacc + u;
      float e2 = __expf(2.f * cacc);
      float th = (e2 - 1.f) / (e2 + 1.f);
      hb[(size_t)(l + 7) * 256] = f2bf(rg * th + (1.f - rg) * xp);
    }
  } else {
    for (int l = LL - 1; l >= 0; --l) {
      half4 v = Ub[(size_t)l * 256];
      float u = (float)v[0], fg = (float)v[1], rg = (float)v[2], xp = (float)v[3];
      cacc = fg * cacc + u;
      float e2 = __expf(2.f * cacc);
      float th = (e2 - 1.f) / (e2 + 1.f);
      hb[(size_t)(l + 7) * 256] = f2bf(rg * th + (1.f - rg) * xp);
    }
  }
}

// ---------------- ConvTranspose as MFMA GEMM ----------------
__global__ __launch_bounds__(256)
void conv_mfma(const ushort* __restrict__ hp, const ushort* __restrict__ Bct,
               const float* __restrict__ ctb, const float* __restrict__ feat,
               float* __restrict__ out, int n0) {
  __shared__ ushort As[128 * 64];
  __shared__ ushort Bs[64 * 64];
  int tid = threadIdx.x;
  int nl = blockIdx.x;
  int lane = tid & 63, w = tid >> 6;
  int wr0 = (w >> 1) * 64, wc0 = (w & 1) * 32;
  int lrow = lane & 15, lk = lane >> 4;
  f32x4 acc[4][2] = {};
  const ushort* hpn = hp + (size_t)nl * LPAD * 256;
  for (int ks = 0; ks < 32; ++ks) {
    int d0 = ks * 64;
    int kk = d0 >> 8, j0 = d0 & 255;
    if (ks) __syncthreads();
#pragma unroll
    for (int i = 0; i < 4; ++i) {
      int p = i * 256 + tid;
      int row = p >> 3, s = (p & 7) ^ (row & 7);
      const ushort* g = hpn + (size_t)(row - kk + 7) * 256 + j0 + s * 8;
      ushort* l = &As[(size_t)(i * 256 + (tid & 192)) * 8];
      __builtin_amdgcn_global_load_lds(GLP(g), LDP(l), 16, 0, 0);
    }
#pragma unroll
    for (int i = 0; i < 2; ++i) {
      int p = i * 256 + tid;
      int row = p >> 3, s = (p & 7) ^ (row & 7);
      const ushort* g = Bct + (size_t)row * 2048 + d0 + s * 8;
      ushort* l = &Bs[(size_t)(i * 256 + (tid & 192)) * 8];
      __builtin_amdgcn_global_load_lds(GLP(g), LDP(l), 16, 0, 0);
    }
    __syncthreads();
#pragma unroll
    for (int s = 0; s < 2; ++s) {
      short8 a[4], b[2];
#pragma unroll
      for (int m = 0; m < 4; ++m) {
        int r = wr0 + m * 16 + lrow;
        int slot = (s * 4 + lk) ^ (r & 7);
        a[m] = *(const short8*)&As[r * 64 + slot * 8];
      }
#pragma unroll
      for (int nn = 0; nn < 2; ++nn) {
        int c = wc0 + nn * 16 + lrow;
        int slot = (s * 4 + lk) ^ (c & 7);
        b[nn] = *(const short8*)&Bs[c * 64 + slot * 8];
      }
#pragma unroll
      for (int m = 0; m < 4; ++m)
#pragma unroll
        for (int nn = 0; nn < 2; ++nn)
          acc[m][nn] = __builtin_amdgcn_mfma_f32_16x16x32_bf16(
              a[m], b[nn], acc[m][nn], 0, 0, 0);
    }
  }
  int n = n0 + nl;
  int b = n >> 7, t = n & 127;
#pragma unroll
  for (int m = 0; m < 4; ++m) {
    int q0 = wr0 + m * 16 + lk * 4;
#pragma unroll
    for (int nn = 0; nn < 2; ++nn) {
      int c = wc0 + nn * 16 + lrow;
      size_t idx = (size_t)b * (CC * TT * QQ) + (size_t)c * (TT * QQ)
                 + (size_t)t * QQ + q0;
      float4v fv = *(const float4v*)&feat[idx];
      float cb = ctb[c];
      float4v ov;
#pragma unroll
      for (int g = 0; g < 4; ++g) ov[g] = acc[m][nn][g] + cb + fv[g];
      *(float4v*)&out[idx] = ov;
    }
  }
}

extern "C" void kernel_launch(void* const* d_in, const int* in_sizes, int n_in,
                              void* d_out, int out_size, void* d_ws, size_t ws_size,
                              hipStream_t stream) {
  const float* feat  = (const float*)d_in[0];
  const float* gamma = (const float*)d_in[1];
  const float* beta  = (const float*)d_in[2];
  const float* w_fwd = (const float*)d_in[3];
  const float* b_fwd = (const float*)d_in[4];
  const float* w_bwd = (const float*)d_in[5];
  const float* b_bwd = (const float*)d_in[6];
  const float* ct_w  = (const float*)d_in[7];
  const float* ct_b  = (const float*)d_in[8];
  float* out = (float*)d_out;

  char* wsb = (char*)d_ws;
  ushort* xT  = (ushort*)wsb;                         // 512*128*64*2 = 8,388,608
  ushort* Wt  = (ushort*)(wsb + 8388608);             // 1024*512*2  = 1,048,576
  ushort* Bct = (ushort*)(wsb + 9437184);             // 64*2048*2   =   262,144
  size_t persist = 9699328;
  size_t per_n = 262144u /*scanU*/ + 69120u /*hp*/;   // 331,264 B
  int NC = 4;
  for (int cand = 512; cand >= 4; cand >>= 1) {
    if (persist + (size_t)cand * per_n <= ws_size) { NC = cand; break; }
  }
  char* dyn = wsb + persist;
  half4*  scanU = (half4*)dyn;
  ushort* hpc   = (ushort*)(dyn + (size_t)NC * 262144u);

  ln_kernel<<<dim3(256), dim3(256), 0, stream>>>(feat, gamma, beta, xT);
  prep_w<<<dim3(2048), dim3(256), 0, stream>>>(w_fwd, w_bwd, Wt);
  prep_bc<<<dim3(512), dim3(256), 0, stream>>>(ct_w, Bct);

  for (int n0 = 0; n0 < NN; n0 += NC) {
    gemm_mfma<<<dim3(8, NC), dim3(256), 0, stream>>>(xT, Wt, b_fwd, b_bwd,
                                                     scanU, n0);
    scan_kernel<<<dim3(NC), dim3(256), 0, stream>>>(scanU, hpc);
    conv_mfma<<<dim3(NC), dim3(256), 0, stream>>>(hpc, Bct, ct_b, feat, out, n0);
  }
}

// Round 4
// 156.065 us; speedup vs baseline: 9.2308x; 1.1762x over previous
//
#include <hip/hip_runtime.h>
#include <math.h>

#define BB 4
#define CC 64
#define TT 128
#define QQ 128
#define KK 8
#define HH 128
#define NN 512
#define LL 121
#define LPAD 135

typedef unsigned short ushort;
typedef __attribute__((ext_vector_type(8))) short short8;
typedef __attribute__((ext_vector_type(4))) float f32x4;
typedef __attribute__((ext_vector_type(4))) float float4v;

#define GLP(p) ((const __attribute__((address_space(1))) void*)(p))
#define LDP(p) ((__attribute__((address_space(3))) void*)(p))

__device__ __forceinline__ ushort f2bf(float x) {
  unsigned u = __float_as_uint(x);
  unsigned r = (u + 0x7FFFu + ((u >> 16) & 1u)) >> 16;
  return (ushort)r;
}

// ---------- LayerNorm over channel dim -> TRANSPOSED bf16 xT[n][q][c] ----------
// single pass: cache all 64 c-values in registers
__global__ __launch_bounds__(256)
void ln_kernel(const float* __restrict__ f, const float* __restrict__ gamma,
               const float* __restrict__ beta, ushort* __restrict__ xT) {
  int p = blockIdx.x * 256 + threadIdx.x;
  int q = p & (QQ - 1);
  int t = (p >> 7) & (TT - 1);
  int b = p >> 14;
  const float* base = f + (size_t)b * CC * TT * QQ + (size_t)t * QQ + q;
  float v[64];
#pragma unroll
  for (int c = 0; c < 64; ++c) v[c] = base[(size_t)c * TT * QQ];
  float s = 0.f, s2 = 0.f;
#pragma unroll
  for (int c = 0; c < 64; ++c) { s += v[c]; s2 += v[c] * v[c]; }
  float mu = s * (1.f / CC);
  float var = s2 * (1.f / CC) - mu * mu;
  float rs = rsqrtf(var + 1e-5f);
  int n = b * TT + t;
  ushort* dst = xT + (size_t)n * (CC * QQ) + (size_t)q * CC;
#pragma unroll
  for (int v8 = 0; v8 < 8; ++v8) {
    short8 ov;
#pragma unroll
    for (int e = 0; e < 8; ++e) {
      int c = v8 * 8 + e;
      ov[e] = (short)f2bf((v[c] - mu) * rs * gamma[c] + beta[c]);
    }
    *(short8*)(dst + v8 * 8) = ov;
  }
}

// ---- Wt[r][d], d = k*64+c (k-major); r permuted h-major-within-pairs ----
__global__ __launch_bounds__(256)
void prep_w(const float* __restrict__ wf, const float* __restrict__ wb,
            ushort* __restrict__ Wt) {
  int idx = blockIdx.x * 256 + threadIdx.x;      // 1024*512
  int r = idx >> 9, d = idx & 511;
  int k = d >> 6, c = d & 63;
  int dir = r >> 9, t = r & 511;
  int h = (t >> 7) * 32 + ((t >> 6) & 1) * 16 + (t & 15);
  int quad = (t >> 4) & 3;
  const float* w = dir ? wb : wf;
  Wt[idx] = f2bf(w[(size_t)(c * 8 + k) * 512 + quad * 128 + h]);
}

// ------- Bct[c][k*256+j] = ct_w[j][c][k] bf16 (64 x 2048) -------
__global__ __launch_bounds__(256)
void prep_bc(const float* __restrict__ ctw, ushort* __restrict__ Bct) {
  int idx = blockIdx.x * 256 + threadIdx.x;      // 64*2048
  int c = idx >> 11, d = idx & 2047;
  int k = d >> 8, j = d & 255;
  Bct[idx] = f2bf(ctw[(size_t)j * (CC * KK) + c * KK + k]);
}

// ------- fused: MFMA GEMM (+unfold gather) -> gates -> in-block SRU scan -> hp -------
__global__ __launch_bounds__(256)
void gemm_mfma(const ushort* __restrict__ xT, const ushort* __restrict__ Wt,
               const float* __restrict__ b_fwd, const float* __restrict__ b_bwd,
               ushort* __restrict__ hp, int n0) {
  __shared__ __align__(16) char smem[35840];
  ushort* As = (ushort*)smem;                 // 16 KB staging
  ushort* Bs = (ushort*)(smem + 16384);       // 16 KB staging
  float2* FUa = (float2*)smem;                // [128][33] float2 = 33792 B
  float2* agg = (float2*)(smem + 33792);      // [32][8]  float2 =  2048 B
  float*  carr = (float*)smem;                // [128][33] float = 16896 B

  int tid = threadIdx.x;
  int nl = blockIdx.y;
  int r0 = blockIdx.x * 128;
  int lane = tid & 63, w = tid >> 6;
  int wr0 = (w >> 1) * 64, wc0 = (w & 1) * 64;
  int lrow = lane & 15, lk = lane >> 4;
  f32x4 acc[4][4] = {};
  const ushort* xTn = xT + (size_t)(n0 + nl) * (CC * QQ);
  for (int ks = 0; ks < 8; ++ks) {
    if (ks) __syncthreads();
#pragma unroll
    for (int i = 0; i < 4; ++i) {            // A: gather-unfold from xT
      int p = i * 256 + tid;
      int row = p >> 3, s = (p & 7) ^ (row & 7);
      const ushort* g = xTn + (size_t)(row + ks) * CC + s * 8;
      ushort* l = &As[(size_t)(i * 256 + (tid & 192)) * 8];
      __builtin_amdgcn_global_load_lds(GLP(g), LDP(l), 16, 0, 0);
    }
#pragma unroll
    for (int i = 0; i < 4; ++i) {            // B
      int p = i * 256 + tid;
      int row = p >> 3, s = (p & 7) ^ (row & 7);
      const ushort* g = Wt + (size_t)(r0 + row) * 512 + ks * 64 + s * 8;
      ushort* l = &Bs[(size_t)(i * 256 + (tid & 192)) * 8];
      __builtin_amdgcn_global_load_lds(GLP(g), LDP(l), 16, 0, 0);
    }
    __syncthreads();
#pragma unroll
    for (int s = 0; s < 2; ++s) {
      short8 a[4], b[4];
#pragma unroll
      for (int m = 0; m < 4; ++m) {
        int r = wr0 + m * 16 + lrow;
        int slot = (s * 4 + lk) ^ (r & 7);
        a[m] = *(const short8*)&As[r * 64 + slot * 8];
      }
#pragma unroll
      for (int nn = 0; nn < 4; ++nn) {
        int j = wc0 + nn * 16 + lrow;
        int slot = (s * 4 + lk) ^ (j & 7);
        b[nn] = *(const short8*)&Bs[j * 64 + slot * 8];
      }
#pragma unroll
      for (int m = 0; m < 4; ++m)
#pragma unroll
        for (int nn = 0; nn < 4; ++nn)
          acc[m][nn] = __builtin_amdgcn_mfma_f32_16x16x32_bf16(
              a[m], b[nn], acc[m][nn], 0, 0, 0);
    }
  }
  // ---- epilogue: gates + in-block scan ----
  int dirf = r0 >> 9;
  int hgroup = (r0 & 511) >> 7;
  int hi = (wc0 >> 6) * 16 + lrow;           // 0..31 within block
  int h = hgroup * 32 + hi;
  const float* bias = dirf ? b_bwd : b_fwd;
  float bf = bias[h], br = bias[128 + h];
  __syncthreads();                           // staging reads complete
  float rgarr[4][4];
  // phase 0: gates -> FU[lidx][hi]
#pragma unroll
  for (int m = 0; m < 4; ++m) {
#pragma unroll
    for (int g = 0; g < 4; ++g) {
      int l = wr0 + m * 16 + lk * 4 + g;
      float xt = acc[m][0][g], fp = acc[m][1][g], rp = acc[m][2][g];
      float fg = 1.f / (1.f + __expf(-(fp + bf)));
      float rg = 1.f / (1.f + __expf(-(rp + br)));
      rgarr[m][g] = rg;
      float u = (1.f - fg) * xt;
      int lidx = dirf ? ((120 - l) & 127) : l;
      FUa[lidx * 33 + hi] = make_float2(fg, u);
    }
  }
  __syncthreads();
  // phase 1: per-(h',chunk) serial scan of 16 elements, keep local prefixes in regs
  int hq = tid & 31, ch = tid >> 5;
  float2 loc[16];
  {
    float F = 1.f, U = 0.f;
#pragma unroll
    for (int i = 0; i < 16; ++i) {
      float2 fu = FUa[(ch * 16 + i) * 33 + hq];
      U = fu.x * U + fu.y;
      F = fu.x * F;
      loc[i] = make_float2(F, U);
    }
  }
  agg[hq * 8 + ch] = loc[15];
  __syncthreads();
  // phase 2: compose chunk prefix, write final c
  {
    float Up = 0.f;
    for (int j = 0; j < ch; ++j) {
      float2 a = agg[hq * 8 + j];
      Up = a.x * Up + a.y;
    }
#pragma unroll
    for (int i = 0; i < 16; ++i)
      carr[(ch * 16 + i) * 33 + hq] = loc[i].y + loc[i].x * Up;
  }
  __syncthreads();
  // phase 3: h_out = r*tanh(c) + (1-r)*xp -> bf16 hp; plus pad-row zeroing
  ushort* hpn = hp + (size_t)nl * LPAD * 256;
  int colbase = dirf * 128 + hgroup * 32;
#pragma unroll
  for (int m = 0; m < 4; ++m) {
#pragma unroll
    for (int g = 0; g < 4; ++g) {
      int l = wr0 + m * 16 + lk * 4 + g;
      if (l <= 120) {
        int lidx = dirf ? (120 - l) : l;
        float c = carr[lidx * 33 + hi];
        float e2 = __expf(2.f * c);
        float th = (e2 - 1.f) / (e2 + 1.f);
        float rg = rgarr[m][g];
        float ho = rg * th + (1.f - rg) * acc[m][3][g];
        hpn[(size_t)(l + 7) * 256 + colbase + hi] = f2bf(ho);
      }
    }
  }
  if (tid < 224) {                            // 14 pad rows x 32 h, 2 per thread
    int e = tid * 2;
    int ri = e >> 5, hh = e & 31;
    int r = ri < 7 ? ri : ri + 121;
    *(unsigned*)&hpn[(size_t)r * 256 + colbase + hh] = 0u;
  }
}

// ---------------- ConvTranspose as MFMA GEMM ----------------
__global__ __launch_bounds__(256)
void conv_mfma(const ushort* __restrict__ hp, const ushort* __restrict__ Bct,
               const float* __restrict__ ctb, const float* __restrict__ feat,
               float* __restrict__ out, int n0) {
  __shared__ ushort As[128 * 64];
  __shared__ ushort Bs[64 * 64];
  int tid = threadIdx.x;
  int nl = blockIdx.x;
  int lane = tid & 63, w = tid >> 6;
  int wr0 = (w >> 1) * 64, wc0 = (w & 1) * 32;
  int lrow = lane & 15, lk = lane >> 4;
  f32x4 acc[4][2] = {};
  const ushort* hpn = hp + (size_t)nl * LPAD * 256;
  for (int ks = 0; ks < 32; ++ks) {
    int d0 = ks * 64;
    int kk = d0 >> 8, j0 = d0 & 255;
    if (ks) __syncthreads();
#pragma unroll
    for (int i = 0; i < 4; ++i) {
      int p = i * 256 + tid;
      int row = p >> 3, s = (p & 7) ^ (row & 7);
      const ushort* g = hpn + (size_t)(row - kk + 7) * 256 + j0 + s * 8;
      ushort* l = &As[(size_t)(i * 256 + (tid & 192)) * 8];
      __builtin_amdgcn_global_load_lds(GLP(g), LDP(l), 16, 0, 0);
    }
#pragma unroll
    for (int i = 0; i < 2; ++i) {
      int p = i * 256 + tid;
      int row = p >> 3, s = (p & 7) ^ (row & 7);
      const ushort* g = Bct + (size_t)row * 2048 + d0 + s * 8;
      ushort* l = &Bs[(size_t)(i * 256 + (tid & 192)) * 8];
      __builtin_amdgcn_global_load_lds(GLP(g), LDP(l), 16, 0, 0);
    }
    __syncthreads();
#pragma unroll
    for (int s = 0; s < 2; ++s) {
      short8 a[4], b[2];
#pragma unroll
      for (int m = 0; m < 4; ++m) {
        int r = wr0 + m * 16 + lrow;
        int slot = (s * 4 + lk) ^ (r & 7);
        a[m] = *(const short8*)&As[r * 64 + slot * 8];
      }
#pragma unroll
      for (int nn = 0; nn < 2; ++nn) {
        int c = wc0 + nn * 16 + lrow;
        int slot = (s * 4 + lk) ^ (c & 7);
        b[nn] = *(const short8*)&Bs[c * 64 + slot * 8];
      }
#pragma unroll
      for (int m = 0; m < 4; ++m)
#pragma unroll
        for (int nn = 0; nn < 2; ++nn)
          acc[m][nn] = __builtin_amdgcn_mfma_f32_16x16x32_bf16(
              a[m], b[nn], acc[m][nn], 0, 0, 0);
    }
  }
  int n = n0 + nl;
  int b = n >> 7, t = n & 127;
#pragma unroll
  for (int m = 0; m < 4; ++m) {
    int q0 = wr0 + m * 16 + lk * 4;
#pragma unroll
    for (int nn = 0; nn < 2; ++nn) {
      int c = wc0 + nn * 16 + lrow;
      size_t idx = (size_t)b * (CC * TT * QQ) + (size_t)c * (TT * QQ)
                 + (size_t)t * QQ + q0;
      float4v fv = *(const float4v*)&feat[idx];
      float cb = ctb[c];
      float4v ov;
#pragma unroll
      for (int g = 0; g < 4; ++g) ov[g] = acc[m][nn][g] + cb + fv[g];
      *(float4v*)&out[idx] = ov;
    }
  }
}

extern "C" void kernel_launch(void* const* d_in, const int* in_sizes, int n_in,
                              void* d_out, int out_size, void* d_ws, size_t ws_size,
                              hipStream_t stream) {
  const float* feat  = (const float*)d_in[0];
  const float* gamma = (const float*)d_in[1];
  const float* beta  = (const float*)d_in[2];
  const float* w_fwd = (const float*)d_in[3];
  const float* b_fwd = (const float*)d_in[4];
  const float* w_bwd = (const float*)d_in[5];
  const float* b_bwd = (const float*)d_in[6];
  const float* ct_w  = (const float*)d_in[7];
  const float* ct_b  = (const float*)d_in[8];
  float* out = (float*)d_out;

  char* wsb = (char*)d_ws;
  ushort* xT  = (ushort*)wsb;                         // 8,388,608 B
  ushort* Wt  = (ushort*)(wsb + 8388608);             // 1,048,576 B
  ushort* Bct = (ushort*)(wsb + 9437184);             //   262,144 B
  size_t persist = 9699328;
  size_t per_n = 69120u;                              // hp only
  int NC = 4;
  for (int cand = 512; cand >= 4; cand >>= 1) {
    if (persist + (size_t)cand * per_n <= ws_size) { NC = cand; break; }
  }
  ushort* hpc = (ushort*)(wsb + persist);

  ln_kernel<<<dim3(256), dim3(256), 0, stream>>>(feat, gamma, beta, xT);
  prep_w<<<dim3(2048), dim3(256), 0, stream>>>(w_fwd, w_bwd, Wt);
  prep_bc<<<dim3(512), dim3(256), 0, stream>>>(ct_w, Bct);

  for (int n0 = 0; n0 < NN; n0 += NC) {
    gemm_mfma<<<dim3(8, NC), dim3(256), 0, stream>>>(xT, Wt, b_fwd, b_bwd,
                                                     hpc, n0);
    conv_mfma<<<dim3(NC), dim3(256), 0, stream>>>(hpc, Bct, ct_b, feat, out, n0);
  }
}